// Round 1
// baseline (1008.427 us; speedup 1.0000x reference)
//
#include <hip/hip_runtime.h>

// CTC forward loss (sum reduction, zero_infinity) for fixed shapes:
// B=32, T=1024, V=1024, L=256, S=2L+1=513, blank=0.
// One block per batch item; 256 threads; states s = tid, tid+256, (tid==0: 512).
// Alpha double-buffered in LDS; emission gathers prefetched PF=4 steps ahead
// (addresses are fixed-column, stride-V — independent of the DP recurrence).

#define NEGF (-1e30f)

constexpr int B_ = 32, T_ = 1024, V_ = 1024, L_ = 256;
constexpr int S_ = 2 * L_ + 1;   // 513
constexpr int NT = 256;          // threads per block (4 waves)
constexpr int PF = 4;            // prefetch depth in time steps

__device__ __forceinline__ float lse3(float a, float b, float c) {
    // log(e^a + e^b + e^c); safe when all == NEGF (result ~ NEGF + log 3)
    float m = fmaxf(fmaxf(a, b), c);
    return m + __logf(__expf(a - m) + __expf(b - m) + __expf(c - m));
}

__global__ __launch_bounds__(NT, 1) void ctc_fwd(
    const float* __restrict__ lp, const int* __restrict__ labels,
    const int* __restrict__ input_lens, const int* __restrict__ label_lens,
    float* __restrict__ out)
{
    __shared__ float Abuf[2][S_ + 4];
    const int b   = blockIdx.x;
    const int tid = threadIdx.x;
    const float* lpb  = lp + (size_t)b * T_ * V_;
    const int*   labb = labels + b * L_;
    const int il = input_lens[b];
    const int ll = label_lens[b];

    // pad two slots below index 0 so reads of alpha[s-1], alpha[s-2] are safe
    float* A0 = &Abuf[0][2];
    float* A1 = &Abuf[1][2];
    if (tid == 0) { A0[-1] = A0[-2] = NEGF; A1[-1] = A1[-2] = NEGF; }

    const int  s0   = tid;
    const int  s1   = tid + NT;
    const bool lead = (tid == 0);
    const int  s2   = S_ - 1;            // 512, even (final blank)

    // extended-label value per state (blank=0 for even s) and skip flag
    const int  e0 = (s0 & 1) ? labb[(s0 - 1) >> 1] : 0;
    const int  e1 = (s1 & 1) ? labb[(s1 - 1) >> 1] : 0;
    const bool k0 = (s0 & 1) && (s0 >= 3) && (labb[(s0 - 1) >> 1] != labb[(s0 - 3) >> 1]);
    const bool k1 = (s1 & 1) && (s1 >= 3) && (labb[(s1 - 1) >> 1] != labb[(s1 - 3) >> 1]);

    // t = 0 init: alpha0[s] = em0[s] for s in {0,1}, else NEG
    A0[s0] = (s0 <= 1) ? lpb[e0] : NEGF;
    A0[s1] = NEGF;                        // s1 >= 256
    if (lead) A0[s2] = NEGF;

    // prefetch emissions for t = 1..PF
    float f0[PF], f1[PF], f2[PF];
    #pragma unroll
    for (int d = 0; d < PF; ++d) {
        int tp = 1 + d; if (tp > T_ - 1) tp = T_ - 1;
        const float* r = lpb + (size_t)tp * V_;
        f0[d] = r[e0];
        f1[d] = r[e1];
        f2[d] = r[0];
    }
    __syncthreads();

    float* cur = A0;
    float* nxt = A1;
    #pragma unroll 4
    for (int t = 1; t < T_; ++t) {
        const int i = (t - 1) & (PF - 1);
        const float em0 = f0[i], em1 = f1[i], em2 = f2[i];

        // issue prefetch for t + PF into the slot just freed (clamped; redundant
        // loads of the last row near the end are harmless)
        int tp = t + PF; if (tp > T_ - 1) tp = T_ - 1;
        const float* r = lpb + (size_t)tp * V_;
        f0[i] = r[e0];
        f1[i] = r[e1];
        f2[i] = r[0];

        const bool act = (t < il);

        const float c0 = cur[s0];
        const float n0 = lse3(c0, cur[s0 - 1], k0 ? cur[s0 - 2] : NEGF) + em0;
        nxt[s0] = act ? n0 : c0;

        const float c1 = cur[s1];
        const float n1 = lse3(c1, cur[s1 - 1], k1 ? cur[s1 - 2] : NEGF) + em1;
        nxt[s1] = act ? n1 : c1;

        if (lead) {
            const float c2 = cur[s2];
            const float n2 = lse3(c2, cur[s2 - 1], NEGF) + em2;
            nxt[s2] = act ? n2 : c2;
        }
        __syncthreads();
        float* tmp = cur; cur = nxt; nxt = tmp;
    }

    if (tid == 0) {
        const int   sl = 2 * ll;
        const float la = cur[sl];
        const float lb = cur[sl - 1];
        const float m  = fmaxf(la, lb);
        float loss = -(m + __logf(__expf(la - m) + __expf(lb - m)));
        if (loss > 1e29f) loss = 0.0f;   // zero_infinity
        atomicAdd(out, loss);
    }
}

extern "C" void kernel_launch(void* const* d_in, const int* in_sizes, int n_in,
                              void* d_out, int out_size, void* d_ws, size_t ws_size,
                              hipStream_t stream) {
    const float* lp     = (const float*)d_in[0];
    const int*   labels = (const int*)d_in[1];
    const int*   il     = (const int*)d_in[2];
    const int*   ll     = (const int*)d_in[3];
    float* out = (float*)d_out;

    // d_out is re-poisoned (0xAA) before every timed replay — zero it here.
    hipMemsetAsync(out, 0, sizeof(float), stream);
    ctc_fwd<<<dim3(B_), dim3(NT), 0, stream>>>(lp, labels, il, ll, out);
}

// Round 2
// 357.602 us; speedup vs baseline: 2.8200x; 2.8200x over previous
//
#include <hip/hip_runtime.h>

// CTC forward loss (sum, zero_infinity), B=32, T=1024, V=1024, L=256, S=513.
// One WAVE (64 lanes) per batch item — no __syncthreads in the DP loop, so
// the rolling 8-step register prefetch of emission gathers is never drained
// by a barrier (gfx950 barriers imply s_waitcnt vmcnt(0)).
// Lane l holds states 8l..8l+7 in registers; lane 63 also holds state 512.
// DP runs in LINEAR probability domain with exact power-of-2 rescaling every
// 8 steps (integer exponent accumulator); loss = Esc*ln2 - log(sum).

constexpr int B_ = 32, T_ = 1024, V_ = 1024, L_ = 256;
constexpr int S_ = 2 * L_ + 1;   // 513
constexpr float LN2F = 0.6931471805599453f;

__global__ __launch_bounds__(64, 1) void ctc_lin(
    const float* __restrict__ lp, const int* __restrict__ labels,
    const int* __restrict__ input_lens, const int* __restrict__ label_lens,
    float* __restrict__ out)
{
    __shared__ float Ls[S_];
    const int b    = blockIdx.x;
    const int lane = threadIdx.x;           // 0..63
    const float* lpb  = lp + (size_t)b * T_ * V_;
    const int*   labb = labels + b * L_;
    const int il = input_lens[b];
    const int ll = label_lens[b];
    const int tend = il < T_ ? il : T_;     // steps t = 1..tend-1 (freeze == stop)

    // Lane l's odd states are s = 8l+2m+1 (m=0..3), label index 4l+m.
    const int e0 = labb[4 * lane + 0];
    const int e1 = labb[4 * lane + 1];
    const int e2 = labb[4 * lane + 2];
    const int e3 = labb[4 * lane + 3];
    const int ep = (lane > 0) ? labb[4 * lane - 1] : -1;
    // skip allowed iff s>=3 and label != label two states back
    const float kf0 = ((8 * lane + 1) >= 3 && e0 != ep) ? 1.f : 0.f;
    const float kf1 = (e1 != e0) ? 1.f : 0.f;
    const float kf2 = (e2 != e1) ? 1.f : 0.f;
    const float kf3 = (e3 != e2) ? 1.f : 0.f;
    // byte offsets for the gathers
    const int o0 = e0 * 4, o1 = e1 * 4, o2 = e2 * 4, o3 = e3 * 4;

    // alpha at t=0 (linear domain)
    float p0 = 0.f, p1 = 0.f, p2 = 0.f, p3 = 0.f, p4 = 0.f,
          p5 = 0.f, p6 = 0.f, p7 = 0.f, p8 = 0.f;
    if (lane == 0) { p0 = __expf(lpb[0]); p1 = __expf(lpb[e0]); }
    int Esc = 0;   // true = stored * 2^{-Esc}

    // rolling prefetch, depth 8
    float gB[8], g0[8], g1[8], g2[8], g3[8];
    #pragma unroll
    for (int i = 0; i < 8; ++i) {
        int tp = 1 + i; if (tp > T_ - 1) tp = T_ - 1;
        const char* r = (const char*)(lpb + (size_t)tp * V_);
        gB[i] = *(const float*)r;
        g0[i] = *(const float*)(r + o0);
        g1[i] = *(const float*)(r + o1);
        g2[i] = *(const float*)(r + o2);
        g3[i] = *(const float*)(r + o3);
    }

    for (int t0 = 1; t0 < tend; t0 += 8) {
        #pragma unroll
        for (int i = 0; i < 8; ++i) {
            const int t = t0 + i;
            // consume slot i
            const float vb = gB[i], v0 = g0[i], v1 = g1[i], v2 = g2[i], v3 = g3[i];
            // refill slot i with row t+8 (clamped; harmless duplicates at the end)
            int tp = t + 8; if (tp > T_ - 1) tp = T_ - 1;
            const char* r = (const char*)(lpb + (size_t)tp * V_);
            gB[i] = *(const float*)r;
            g0[i] = *(const float*)(r + o0);
            g1[i] = *(const float*)(r + o1);
            g2[i] = *(const float*)(r + o2);
            g3[i] = *(const float*)(r + o3);

            if (t < tend) {   // wave-uniform
                float pm1 = __shfl_up(p7, 1);   // state 8l-1
                float pm2 = __shfl_up(p6, 1);   // state 8l-2
                if (lane == 0) { pm1 = 0.f; pm2 = 0.f; }
                const float pb = __expf(vb);
                const float q0 = __expf(v0), q1 = __expf(v1),
                            q2 = __expf(v2), q3 = __expf(v3);
                const float n0 = (p0 + pm1) * pb;
                const float n1 = fmaf(kf0, pm2, p1 + p0) * q0;
                const float n2 = (p2 + p1) * pb;
                const float n3 = fmaf(kf1, p1, p3 + p2) * q1;
                const float n4 = (p4 + p3) * pb;
                const float n5 = fmaf(kf2, p3, p5 + p4) * q2;
                const float n6 = (p6 + p5) * pb;
                const float n7 = fmaf(kf3, p5, p7 + p6) * q3;
                const float n8 = (p8 + p7) * pb;   // state 512 (lane 63); dup elsewhere
                p0 = n0; p1 = n1; p2 = n2; p3 = n3; p4 = n4;
                p5 = n5; p6 = n6; p7 = n7; p8 = n8;
            }
        }
        // exact pow2 rescale: bring wave-max to [1,2)
        float m = fmaxf(fmaxf(fmaxf(fmaxf(p0, p1), fmaxf(p2, p3)),
                              fmaxf(fmaxf(p4, p5), fmaxf(p6, p7))), p8);
        #pragma unroll
        for (int off = 32; off >= 1; off >>= 1)
            m = fmaxf(m, __shfl_xor(m, off));
        const unsigned eb = (__float_as_uint(m) >> 23) & 0xffu;
        if (eb >= 1u && eb <= 253u) {
            const float f = __uint_as_float((254u - eb) << 23);  // 2^(127-eb), exact
            p0 *= f; p1 *= f; p2 *= f; p3 *= f; p4 *= f;
            p5 *= f; p6 *= f; p7 *= f; p8 *= f;
            Esc += 127 - (int)eb;
        }
    }

    // epilogue: collect the two needed states via LDS (single wave)
    Ls[8 * lane + 0] = p0; Ls[8 * lane + 1] = p1;
    Ls[8 * lane + 2] = p2; Ls[8 * lane + 3] = p3;
    Ls[8 * lane + 4] = p4; Ls[8 * lane + 5] = p5;
    Ls[8 * lane + 6] = p6; Ls[8 * lane + 7] = p7;
    if (lane == 63) Ls[512] = p8;
    __syncthreads();
    if (lane == 0) {
        const int sl = 2 * ll;
        const float la  = Ls[sl];
        const float lb  = (sl >= 1) ? Ls[sl - 1] : 0.f;
        const float tot = la + lb;
        float loss = (float)Esc * LN2F - __logf(tot);
        if (!(loss <= 1e29f)) loss = 0.f;   // zero_infinity (tot==0 -> +inf -> 0)
        atomicAdd(out, loss);
    }
}

extern "C" void kernel_launch(void* const* d_in, const int* in_sizes, int n_in,
                              void* d_out, int out_size, void* d_ws, size_t ws_size,
                              hipStream_t stream) {
    const float* lp     = (const float*)d_in[0];
    const int*   labels = (const int*)d_in[1];
    const int*   il     = (const int*)d_in[2];
    const int*   ll     = (const int*)d_in[3];
    float* out = (float*)d_out;

    hipMemsetAsync(out, 0, sizeof(float), stream);   // d_out is re-poisoned each replay
    ctc_lin<<<dim3(B_), dim3(64), 0, stream>>>(lp, labels, il, ll, out);
}